// Round 10
// baseline (595.738 us; speedup 1.0000x reference)
//
#include <hip/hip_runtime.h>
#include <hip/hip_bf16.h>

#define BS   8192
#define DIM  768
#define BM   256
#define BN   128
#define BK   128   // one scaled-MFMA K per tile; 6 tiles total

typedef float f32x4 __attribute__((ext_vector_type(4)));
typedef int   i32x4 __attribute__((ext_vector_type(4)));
typedef int   i32x8 __attribute__((ext_vector_type(8)));

__device__ __forceinline__ void async16(const void* g, void* l) {
    __builtin_amdgcn_global_load_lds(
        (const __attribute__((address_space(1))) unsigned int*)g,
        (__attribute__((address_space(3))) unsigned int*)l,
        16, 0, 0);
}

// One wave per row: L2-norm both embeddings, emit fp8 e4m3, diag sim in fp32.
// Blocks 0..63 also zero rowsum/colsum (replaces the hipMemsetAsync dispatch).
__global__ __launch_bounds__(256) void normalize_kernel(
    const float* __restrict__ text, const float* __restrict__ ctr,
    unsigned char* __restrict__ tq, unsigned char* __restrict__ cq,
    float* __restrict__ sim, float* __restrict__ rowsum, float* __restrict__ colsum) {
    if (blockIdx.x < 64) {
        const int i = blockIdx.x * 256 + threadIdx.x;   // covers 16384 = 2*BS
        rowsum[i] = 0.f;
        colsum[i] = 0.f;
    }
    const int lane = threadIdx.x & 63;
    const int row  = blockIdx.x * 4 + (threadIdx.x >> 6);
    const size_t base = (size_t)row * DIM;

    float4 t[3], c[3];
    float st = 0.f, sc = 0.f, sd = 0.f;
#pragma unroll
    for (int i = 0; i < 3; ++i) {
        t[i] = *(const float4*)&text[base + lane * 4 + i * 256];
        c[i] = *(const float4*)&ctr [base + lane * 4 + i * 256];
        st += t[i].x*t[i].x + t[i].y*t[i].y + t[i].z*t[i].z + t[i].w*t[i].w;
        sc += c[i].x*c[i].x + c[i].y*c[i].y + c[i].z*c[i].z + c[i].w*c[i].w;
        sd += t[i].x*c[i].x + t[i].y*c[i].y + t[i].z*c[i].z + t[i].w*c[i].w;
    }
#pragma unroll
    for (int off = 1; off < 64; off <<= 1) {
        st += __shfl_xor(st, off);
        sc += __shfl_xor(sc, off);
        sd += __shfl_xor(sd, off);
    }
    const float invt = 1.0f / fmaxf(sqrtf(st), 1e-8f);
    const float invc = 1.0f / fmaxf(sqrtf(sc), 1e-8f);
#pragma unroll
    for (int i = 0; i < 3; ++i) {
        unsigned int wt = (unsigned int)__builtin_amdgcn_cvt_pk_fp8_f32(t[i].x * invt, t[i].y * invt, 0, false);
        wt = (unsigned int)__builtin_amdgcn_cvt_pk_fp8_f32(t[i].z * invt, t[i].w * invt, (int)wt, true);
        unsigned int wcq = (unsigned int)__builtin_amdgcn_cvt_pk_fp8_f32(c[i].x * invc, c[i].y * invc, 0, false);
        wcq = (unsigned int)__builtin_amdgcn_cvt_pk_fp8_f32(c[i].z * invc, c[i].w * invc, (int)wcq, true);
        *(unsigned int*)&tq[base + lane * 4 + i * 256] = wt;
        *(unsigned int*)&cq[base + lane * 4 + i * 256] = wcq;
    }
    if (lane == 0) sim[row] = sd * invt * invc;
}

// MX-scaled fp8 GEMM (unit scales) -- round 14: R9 geometry with the spill
// FIXED. R9 evidence: occupancy doubled to 40% as intended, but WRITE_SIZE
// 18.4->189 MB / FETCH 27.7->92.5 MB = ~180 B/thread of scratch traffic ->
// BW-bound at 2 TB/s -> 140us. Root cause: launch_bounds(512,4) = 128-reg
// budget; acc[8][2]=64 AGPR + rp[8][4] (32 floats live across the WHOLE
// epilogue) + bf/af + staging addrs ~= 150 -> spill. Fix: per-mt epilogue
// (rp[4] live at a time, reduce+atomic immediately). Loop live set ~56 arch
// VGPR + 64 AGPR = ~120 <= 128. Everything else verbatim from R9 (passed,
// absmax=0). 2 blocks/CU (48KB LDS, 128 regs) + simple 2-barrier loop:
// inter-block TLP hides the stage drain (m114/m148; R3's 3blk/CU evidence).
// Primary verification: WRITE_SIZE back to ~20 MB, occupancy ~40%.
// LDS layout per operand: [kc(4)][row][32B], halves swizzled by (kc&1):
// conflict-free (same pattern as all rounds, SQ_LDS_BANK_CONFLICT=0).
__global__ __launch_bounds__(512, 4) void gemm_lse_kernel(
    const unsigned char* __restrict__ tq, const unsigned char* __restrict__ cq,
    float* __restrict__ rowsum, float* __restrict__ colsum) {
    __shared__ char ldsA[BM * BK];   // 32 KB
    __shared__ char ldsB[BN * BK];   // 16 KB

    const int tid = threadIdx.x;

    // XCD-banded swizzle: XCD x owns tile-row-bands [4x, 4x+4), sweeping cols.
    const int bid = blockIdx.x;              // 2048 blocks = 32 bands x 64 cols
    const int xcd = bid & 7, idx = bid >> 3;
    const int rowBase = (xcd * 4 + (idx & 3)) * BM;
    const int colBase = (idx >> 2) * BN;

    const int wave = tid >> 6, lane = tid & 63;
    const int wr = wave >> 2, wc = wave & 3;   // 2x4 wave grid: 128x32 per wave
    const int quad = lane >> 4, l16 = lane & 15;

    // Staging. A: 2048 16B chunks/tile (4/thread); B: 1024 (2/thread).
    // chunk p -> kc, row, logical-half hl = (p&1)^(kc&1); LDS dest linear.
    int goffA[4], pA[4];
#pragma unroll
    for (int i = 0; i < 4; ++i) {
        const int p  = tid + i * 512;
        const int kc = p >> 9;               // A: 512 chunks per kc block
        const int row = (p >> 1) & 255;
        const int hl  = (p & 1) ^ (kc & 1);
        goffA[i] = row * DIM + kc * 32 + hl * 16;
        pA[i]    = p * 16;
    }
    int goffB[2], pB[2];
#pragma unroll
    for (int i = 0; i < 2; ++i) {
        const int p  = tid + i * 512;
        const int kc = p >> 8;               // B: 256 chunks per kc block
        const int row = (p >> 1) & 127;
        const int hl  = (p & 1) ^ (kc & 1);
        goffB[i] = row * DIM + kc * 32 + hl * 16;
        pB[i]    = p * 16;
    }
    const unsigned char* gA = tq + (size_t)rowBase * DIM;
    const unsigned char* gB = cq + (size_t)colBase * DIM;

    // Fragment addressing: lane (quad,l16) needs k-block kc=quad of its row;
    // physical half = logical half ^ (quad&1).
    const int sw = quad & 1;
    const int abase = quad * 8192 + (wr * 128 + l16) * 32;  // + mt*512
    const int bbase = quad * 4096 + (wc * 32  + l16) * 32;  // + nt*512

    f32x4 acc[8][2];
#pragma unroll
    for (int mt = 0; mt < 8; ++mt)
#pragma unroll
        for (int nt = 0; nt < 2; ++nt)
            acc[mt][nt] = (f32x4){0.f, 0.f, 0.f, 0.f};

    for (int t = 0; t < 6; ++t) {
        const int k0 = t * BK;
#pragma unroll
        for (int i = 0; i < 4; ++i) async16(gA + goffA[i] + k0, ldsA + pA[i]);
#pragma unroll
        for (int i = 0; i < 2; ++i) async16(gB + goffB[i] + k0, ldsB + pB[i]);
        __syncthreads();   // implicit vmcnt(0): tile staged

        i32x8 bf[2];
#pragma unroll
        for (int nt = 0; nt < 2; ++nt) {
            i32x4 lo = *(const i32x4*)(ldsB + bbase + nt * 512 + sw * 16);
            i32x4 hi = *(const i32x4*)(ldsB + bbase + nt * 512 + (sw ^ 1) * 16);
            bf[nt] = __builtin_shufflevector(lo, hi, 0, 1, 2, 3, 4, 5, 6, 7);
        }
#pragma unroll
        for (int mt = 0; mt < 8; ++mt) {
            i32x4 lo = *(const i32x4*)(ldsA + abase + mt * 512 + sw * 16);
            i32x4 hi = *(const i32x4*)(ldsA + abase + mt * 512 + (sw ^ 1) * 16);
            i32x8 af = __builtin_shufflevector(lo, hi, 0, 1, 2, 3, 4, 5, 6, 7);
            acc[mt][0] = __builtin_amdgcn_mfma_scale_f32_16x16x128_f8f6f4(
                af, bf[0], acc[mt][0], 0, 0, 0, 127, 0, 127);
            acc[mt][1] = __builtin_amdgcn_mfma_scale_f32_16x16x128_f8f6f4(
                af, bf[1], acc[mt][1], 0, 0, 0, 127, 0, 127);
        }
        __syncthreads();   // reads done before next tile overwrites
    }

    // Epilogue, per-mt to cap register pressure (R9 spill fix).
    // D layout: col = l16 (ctr idx), row = quad*4 + reg (text idx).
    float cp0 = 0.f, cp1 = 0.f;   // col partials over this wave's 128 rows
#pragma unroll
    for (int mt = 0; mt < 8; ++mt) {
        float rp[4];
#pragma unroll
        for (int r = 0; r < 4; ++r) {
            const float e0 = __expf(acc[mt][0][r]);   // S in [-1,1]: no max needed
            const float e1 = __expf(acc[mt][1][r]);
            rp[r] = e0 + e1;
            cp0 += e0;
            cp1 += e1;
        }
#pragma unroll
        for (int r = 0; r < 4; ++r) {
            float v = rp[r];
            v += __shfl_xor(v, 1);
            v += __shfl_xor(v, 2);
            v += __shfl_xor(v, 4);
            v += __shfl_xor(v, 8);
            rp[r] = v;
        }
        if (l16 == 0) {
#pragma unroll
            for (int r = 0; r < 4; ++r)
                atomicAdd(&rowsum[rowBase + wr * 128 + mt * 16 + quad * 4 + r], rp[r]);
        }
    }
    {
        float v = cp0;
        v += __shfl_xor(v, 16);
        v += __shfl_xor(v, 32);
        if (quad == 0)
            atomicAdd(&colsum[colBase + wc * 32 + l16], v);
    }
    {
        float v = cp1;
        v += __shfl_xor(v, 16);
        v += __shfl_xor(v, 32);
        if (quad == 0)
            atomicAdd(&colsum[colBase + wc * 32 + 16 + l16], v);
    }
}

__global__ __launch_bounds__(1024) void finalize_kernel(
    const float* __restrict__ rowsum, const float* __restrict__ colsum,
    const float* __restrict__ sim, float* __restrict__ out) {
    const int tid = threadIdx.x;
    float acc = 0.f;
#pragma unroll
    for (int i = 0; i < 2; ++i) {
        const int j = (tid + i * 1024) * 4;
        float4 rs = *(const float4*)&rowsum[j];
        float4 cs = *(const float4*)&colsum[j];
        float4 sm = *(const float4*)&sim[j];
        acc += __logf(rs.x) + __logf(rs.y) + __logf(rs.z) + __logf(rs.w);
        acc += __logf(cs.x) + __logf(cs.y) + __logf(cs.z) + __logf(cs.w);
        acc -= 2.f * (sm.x + sm.y + sm.z + sm.w);
    }
#pragma unroll
    for (int off = 1; off < 64; off <<= 1) acc += __shfl_xor(acc, off);
    __shared__ float red[16];
    const int wave = tid >> 6, lane = tid & 63;
    if (lane == 0) red[wave] = acc;
    __syncthreads();
    if (tid == 0) {
        float s = 0.f;
#pragma unroll
        for (int w = 0; w < 16; ++w) s += red[w];
        out[0] = s / (float)BS;
    }
}

extern "C" void kernel_launch(void* const* d_in, const int* in_sizes, int n_in,
                              void* d_out, int out_size, void* d_ws, size_t ws_size,
                              hipStream_t stream) {
    const float* text = (const float*)d_in[0];
    const float* ctr  = (const float*)d_in[1];

    char* ws = (char*)d_ws;
    const size_t embBytes = (size_t)BS * DIM;   // fp8: 6,291,456 bytes each
    unsigned char* tq = (unsigned char*)ws;
    unsigned char* cq = (unsigned char*)(ws + embBytes);
    float* sim    = (float*)(ws + 2 * embBytes);
    float* rowsum = (float*)(ws + 2 * embBytes + BS * sizeof(float));
    float* colsum = (float*)(ws + 2 * embBytes + 2 * BS * sizeof(float));

    normalize_kernel<<<BS / 4, 256, 0, stream>>>(text, ctr, tq, cq, sim, rowsum, colsum);

    gemm_lse_kernel<<<(BS / BM) * (BS / BN), 512, 0, stream>>>(tq, cq, rowsum, colsum);

    finalize_kernel<<<1, 1024, 0, stream>>>(rowsum, colsum, sim, (float*)d_out);
}

// Round 11
// 169.640 us; speedup vs baseline: 3.5118x; 3.5118x over previous
//
#include <hip/hip_runtime.h>
#include <hip/hip_bf16.h>

#define BS   8192
#define DIM  768
#define BM   256
#define BK   128   // one scaled-MFMA K per tile; 6 tiles total

typedef float f32x4 __attribute__((ext_vector_type(4)));
typedef int   i32x4 __attribute__((ext_vector_type(4)));
typedef int   i32x8 __attribute__((ext_vector_type(8)));

__device__ __forceinline__ void async16(const void* g, void* l) {
    __builtin_amdgcn_global_load_lds(
        (const __attribute__((address_space(1))) unsigned int*)g,
        (__attribute__((address_space(3))) unsigned int*)l,
        16, 0, 0);
}

// One wave per row: L2-norm both embeddings, emit fp8 e4m3, diag sim in fp32.
// Blocks 0..63 also zero rowsum/colsum (replaces the hipMemsetAsync dispatch).
__global__ __launch_bounds__(256) void normalize_kernel(
    const float* __restrict__ text, const float* __restrict__ ctr,
    unsigned char* __restrict__ tq, unsigned char* __restrict__ cq,
    float* __restrict__ sim, float* __restrict__ rowsum, float* __restrict__ colsum) {
    if (blockIdx.x < 64) {
        const int i = blockIdx.x * 256 + threadIdx.x;   // covers 16384 = 2*BS
        rowsum[i] = 0.f;
        colsum[i] = 0.f;
    }
    const int lane = threadIdx.x & 63;
    const int row  = blockIdx.x * 4 + (threadIdx.x >> 6);
    const size_t base = (size_t)row * DIM;

    float4 t[3], c[3];
    float st = 0.f, sc = 0.f, sd = 0.f;
#pragma unroll
    for (int i = 0; i < 3; ++i) {
        t[i] = *(const float4*)&text[base + lane * 4 + i * 256];
        c[i] = *(const float4*)&ctr [base + lane * 4 + i * 256];
        st += t[i].x*t[i].x + t[i].y*t[i].y + t[i].z*t[i].z + t[i].w*t[i].w;
        sc += c[i].x*c[i].x + c[i].y*c[i].y + c[i].z*c[i].z + c[i].w*c[i].w;
        sd += t[i].x*c[i].x + t[i].y*c[i].y + t[i].z*c[i].z + t[i].w*c[i].w;
    }
#pragma unroll
    for (int off = 1; off < 64; off <<= 1) {
        st += __shfl_xor(st, off);
        sc += __shfl_xor(sc, off);
        sd += __shfl_xor(sd, off);
    }
    const float invt = 1.0f / fmaxf(sqrtf(st), 1e-8f);
    const float invc = 1.0f / fmaxf(sqrtf(sc), 1e-8f);
#pragma unroll
    for (int i = 0; i < 3; ++i) {
        unsigned int wt = (unsigned int)__builtin_amdgcn_cvt_pk_fp8_f32(t[i].x * invt, t[i].y * invt, 0, false);
        wt = (unsigned int)__builtin_amdgcn_cvt_pk_fp8_f32(t[i].z * invt, t[i].w * invt, (int)wt, true);
        unsigned int wcq = (unsigned int)__builtin_amdgcn_cvt_pk_fp8_f32(c[i].x * invc, c[i].y * invc, 0, false);
        wcq = (unsigned int)__builtin_amdgcn_cvt_pk_fp8_f32(c[i].z * invc, c[i].w * invc, (int)wcq, true);
        *(unsigned int*)&tq[base + lane * 4 + i * 256] = wt;
        *(unsigned int*)&cq[base + lane * 4 + i * 256] = wcq;
    }
    if (lane == 0) sim[row] = sd * invt * invc;
}

// MX-scaled fp8 GEMM (unit scales) -- round 15 FINAL: exact R8 configuration,
// the session optimum (gemm 93us, total 170.4us, absmax=0).
// Why this is terminal -- the full sampled landscape:
//   schedules @256^2/1blk: 2ph=118, counted-vmcnt=118, 4ph-no-barriers=93-102,
//     4ph+phase-barriers=128 (barriers cost at K=768's 6 iters)
//   geometry: 128^2/4w/3blk=107 (TLP up, compute:stage ratio down)
//   occupancy rebalance (256x128/4w-per-SIMD): R9=140 (graceful spill 189MB),
//     R10=558 (acc[8][2] scratch-demoted wholesale: VGPR=64, WRITE=1.1GB,
//     3KB/thread C-traffic). PROVEN: >=4 waves/SIMD + acc>=64 cannot fit the
//     128-reg cap; large-acc/1-blk strictly dominates.
//   fusion: fused-finalize tail = +21us (1024x threadfence + hot XCD line);
//     persistent grid-barrier = +70us. Dispatch boundaries are cheaper.
// Remaining gap to the 4.66PF MX ceiling (~22us) is latency exposure at 6
// K-iterations -- unreachable from plain-HIP scheduling per this session's
// 8-structure sample and guide m248v2 (8ph/2ph=1.10x at short K).
// Schedule: phase p in {0..3}: {ds_read A-pair(p+1) || stage quarter(t+1)};
// lgkmcnt(4); setprio(1) 8xMFMA setprio(0). Boundary: lgkm(0); mid-barrier;
// stage t+2.Q0 into buf[cur]; MFMA pair3; vmcnt(2) (never 0 mid-loop); barrier.
// LDS [kc(4)][row(256)][32B], halves swizzled by (kc&1): conflict-free.
__global__ __launch_bounds__(512, 2) void gemm_lse_kernel(
    const unsigned char* __restrict__ tq, const unsigned char* __restrict__ cq,
    float* __restrict__ rowsum, float* __restrict__ colsum) {
    __shared__ char ldsA[2][BM * BK];   // 2 x 32 KB
    __shared__ char ldsB[2][BM * BK];   // 2 x 32 KB

    const int tid = threadIdx.x;

    // XCD-banded swizzle: XCD x owns tile-rows [4x, 4x+4), sweeping columns.
    const int bid = blockIdx.x;              // 1024 blocks = 32x32 tiles
    const int xcd = bid & 7, idx = bid >> 3;
    const int tileCol = idx >> 2, rowInBand = idx & 3;
    const int rowBase = (xcd * 4 + rowInBand) * BM;
    const int colBase = tileCol * BM;

    const int wave = tid >> 6, lane = tid & 63;
    const int wr = wave >> 2, wc = wave & 3;   // 2x4 wave grid: 128x64 per wave
    const int quad = lane >> 4, l16 = lane & 15;

    // Staging: 2048 16B chunks per operand tile; thread owns chunk tid+i*512
    // (quarter i). chunk p -> kc = p>>9, row = (p>>1)&255,
    // logical-half = (p&1) ^ (kc&1). LDS dest linear (wave-uniform + lane*16).
    int goff[4], p16[4];
#pragma unroll
    for (int i = 0; i < 4; ++i) {
        const int p  = tid + i * 512;
        const int kc = p >> 9;
        const int row = (p >> 1) & 255;
        const int hl  = (p & 1) ^ (kc & 1);
        goff[i] = row * DIM + kc * 32 + hl * 16;
        p16[i]  = p * 16;
    }
    const unsigned char* gA = tq + (size_t)rowBase * DIM;
    const unsigned char* gB = cq + (size_t)colBase * DIM;

#define STAGE(buf, t, i)                                            \
    do {                                                            \
        async16(gA + goff[i] + (t) * BK, &ldsA[buf][p16[i]]);       \
        async16(gB + goff[i] + (t) * BK, &ldsB[buf][p16[i]]);       \
    } while (0)

    // Fragment addressing: lane (quad,l16) needs k-block kc=quad of its row;
    // physical half = logical half ^ (quad&1).
    const int sw = quad & 1;
    int aoff[8], boff[4];
#pragma unroll
    for (int mt = 0; mt < 8; ++mt) aoff[mt] = quad * 8192 + (wr * 128 + mt * 16 + l16) * 32;
#pragma unroll
    for (int nt = 0; nt < 4; ++nt) boff[nt] = quad * 8192 + (wc * 64 + nt * 16 + l16) * 32;

#define RD_A(dst, mt, buf)                                                     \
    do {                                                                       \
        i32x4 lo = *(const i32x4*)(ldsA[buf] + aoff[mt] + sw * 16);            \
        i32x4 hi = *(const i32x4*)(ldsA[buf] + aoff[mt] + (sw ^ 1) * 16);      \
        dst = __builtin_shufflevector(lo, hi, 0, 1, 2, 3, 4, 5, 6, 7);         \
    } while (0)
#define RD_B(dst, nt, buf)                                                     \
    do {                                                                       \
        i32x4 lo = *(const i32x4*)(ldsB[buf] + boff[nt] + sw * 16);            \
        i32x4 hi = *(const i32x4*)(ldsB[buf] + boff[nt] + (sw ^ 1) * 16);      \
        dst = __builtin_shufflevector(lo, hi, 0, 1, 2, 3, 4, 5, 6, 7);         \
    } while (0)
#define MFMA8(a0, a1, m0, m1)                                                  \
    do {                                                                       \
        acc[m0][0] = __builtin_amdgcn_mfma_scale_f32_16x16x128_f8f6f4(a0, bf0, acc[m0][0], 0, 0, 0, 127, 0, 127); \
        acc[m0][1] = __builtin_amdgcn_mfma_scale_f32_16x16x128_f8f6f4(a0, bf1, acc[m0][1], 0, 0, 0, 127, 0, 127); \
        acc[m0][2] = __builtin_amdgcn_mfma_scale_f32_16x16x128_f8f6f4(a0, bf2, acc[m0][2], 0, 0, 0, 127, 0, 127); \
        acc[m0][3] = __builtin_amdgcn_mfma_scale_f32_16x16x128_f8f6f4(a0, bf3, acc[m0][3], 0, 0, 0, 127, 0, 127); \
        acc[m1][0] = __builtin_amdgcn_mfma_scale_f32_16x16x128_f8f6f4(a1, bf0, acc[m1][0], 0, 0, 0, 127, 0, 127); \
        acc[m1][1] = __builtin_amdgcn_mfma_scale_f32_16x16x128_f8f6f4(a1, bf1, acc[m1][1], 0, 0, 0, 127, 0, 127); \
        acc[m1][2] = __builtin_amdgcn_mfma_scale_f32_16x16x128_f8f6f4(a1, bf2, acc[m1][2], 0, 0, 0, 127, 0, 127); \
        acc[m1][3] = __builtin_amdgcn_mfma_scale_f32_16x16x128_f8f6f4(a1, bf3, acc[m1][3], 0, 0, 0, 127, 0, 127); \
    } while (0)
#define SBAR()  __builtin_amdgcn_sched_barrier(0)

    f32x4 acc[8][4];
#pragma unroll
    for (int mt = 0; mt < 8; ++mt)
#pragma unroll
        for (int nt = 0; nt < 4; ++nt)
            acc[mt][nt] = (f32x4){0.f, 0.f, 0.f, 0.f};

    // Prologue: stage tile 0 fully (8 loads) + tile 1 quarter 0 (2 loads);
    // wait vmcnt(2): tile 0 landed, t1.Q0 in flight.
    STAGE(0, 0, 0); STAGE(0, 0, 1); STAGE(0, 0, 2); STAGE(0, 0, 3);
    SBAR();
    STAGE(1, 1, 0);
    SBAR();
    asm volatile("s_waitcnt vmcnt(2)" ::: "memory");
    SBAR();
    __builtin_amdgcn_s_barrier();

#pragma unroll
    for (int t = 0; t < 6; ++t) {
        const int cur = t & 1;
        i32x8 bf0, bf1, bf2, bf3, aE0, aE1, aO0, aO1;

        // Pre-phase reads: all B (8 b128) + A pair0 (4 b128).
        RD_B(bf0, 0, cur); RD_B(bf1, 1, cur); RD_B(bf2, 2, cur); RD_B(bf3, 3, cur);
        RD_A(aE0, 0, cur); RD_A(aE1, 1, cur);

        // ph0: prefetch A pair1; stage Q1(t+1); wait(4); MFMA pair0.
        RD_A(aO0, 2, cur); RD_A(aO1, 3, cur);
        if (t < 5) STAGE(cur ^ 1, t + 1, 1);
        asm volatile("s_waitcnt lgkmcnt(4)" ::: "memory");
        SBAR();
        __builtin_amdgcn_s_setprio(1);
        MFMA8(aE0, aE1, 0, 1);
        __builtin_amdgcn_s_setprio(0);

        // ph1: prefetch A pair2; stage Q2(t+1); wait(4); MFMA pair1.
        RD_A(aE0, 4, cur); RD_A(aE1, 5, cur);
        if (t < 5) STAGE(cur ^ 1, t + 1, 2);
        asm volatile("s_waitcnt lgkmcnt(4)" ::: "memory");
        SBAR();
        __builtin_amdgcn_s_setprio(1);
        MFMA8(aO0, aO1, 2, 3);
        __builtin_amdgcn_s_setprio(0);

        // ph2: prefetch A pair3; stage Q3(t+1); wait(4); MFMA pair2.
        RD_A(aO0, 6, cur); RD_A(aO1, 7, cur);
        if (t < 5) STAGE(cur ^ 1, t + 1, 3);
        asm volatile("s_waitcnt lgkmcnt(4)" ::: "memory");
        SBAR();
        __builtin_amdgcn_s_setprio(1);
        MFMA8(aE0, aE1, 4, 5);
        __builtin_amdgcn_s_setprio(0);

        // ph3: wait(0); MFMA pair3.
        asm volatile("s_waitcnt lgkmcnt(0)" ::: "memory");
        SBAR();
        __builtin_amdgcn_s_setprio(1);
        MFMA8(aO0, aO1, 6, 7);
        __builtin_amdgcn_s_setprio(0);

        // Boundary: mid-barrier (reads of buf[cur] done block-wide) ->
        // issue t+2.Q0 into buf[cur]; counted vmcnt; barrier.
        if (t < 5) {
            __builtin_amdgcn_s_barrier();
            SBAR();
            if (t < 4) {
                STAGE(cur, t + 2, 0);
                SBAR();
                asm volatile("s_waitcnt vmcnt(2)" ::: "memory");
            } else {
                asm volatile("s_waitcnt vmcnt(0)" ::: "memory");
            }
            SBAR();
            __builtin_amdgcn_s_barrier();
        }
    }

    // Epilogue. D layout: col = l16 (ctr idx), row = quad*4 + reg (text idx).
    float rp[8][4];   // [mt][reg] partials over this wave's 64 cols
    float cp[4];      // [nt] partials over this wave's 128 rows
#pragma unroll
    for (int mt = 0; mt < 8; ++mt)
#pragma unroll
        for (int r = 0; r < 4; ++r) rp[mt][r] = 0.f;
#pragma unroll
    for (int nt = 0; nt < 4; ++nt) cp[nt] = 0.f;

#pragma unroll
    for (int mt = 0; mt < 8; ++mt)
#pragma unroll
        for (int nt = 0; nt < 4; ++nt)
#pragma unroll
            for (int r = 0; r < 4; ++r) {
                const float e = __expf(acc[mt][nt][r]);   // S in [-1,1]: no max needed
                rp[mt][r] += e;
                cp[nt]    += e;
            }

#pragma unroll
    for (int mt = 0; mt < 8; ++mt)
#pragma unroll
        for (int r = 0; r < 4; ++r) {
            float v = rp[mt][r];
            v += __shfl_xor(v, 1);
            v += __shfl_xor(v, 2);
            v += __shfl_xor(v, 4);
            v += __shfl_xor(v, 8);
            rp[mt][r] = v;
        }
    if (l16 == 0) {
#pragma unroll
        for (int mt = 0; mt < 8; ++mt)
#pragma unroll
            for (int r = 0; r < 4; ++r)
                atomicAdd(&rowsum[rowBase + wr * 128 + mt * 16 + quad * 4 + r], rp[mt][r]);
    }
#pragma unroll
    for (int nt = 0; nt < 4; ++nt) {
        float v = cp[nt];
        v += __shfl_xor(v, 16);
        v += __shfl_xor(v, 32);
        if (quad == 0)
            atomicAdd(&colsum[colBase + wc * 64 + nt * 16 + l16], v);
    }
}

__global__ __launch_bounds__(1024) void finalize_kernel(
    const float* __restrict__ rowsum, const float* __restrict__ colsum,
    const float* __restrict__ sim, float* __restrict__ out) {
    const int tid = threadIdx.x;
    float acc = 0.f;
#pragma unroll
    for (int i = 0; i < 2; ++i) {
        const int j = (tid + i * 1024) * 4;
        float4 rs = *(const float4*)&rowsum[j];
        float4 cs = *(const float4*)&colsum[j];
        float4 sm = *(const float4*)&sim[j];
        acc += __logf(rs.x) + __logf(rs.y) + __logf(rs.z) + __logf(rs.w);
        acc += __logf(cs.x) + __logf(cs.y) + __logf(cs.z) + __logf(cs.w);
        acc -= 2.f * (sm.x + sm.y + sm.z + sm.w);
    }
#pragma unroll
    for (int off = 1; off < 64; off <<= 1) acc += __shfl_xor(acc, off);
    __shared__ float red[16];
    const int wave = tid >> 6, lane = tid & 63;
    if (lane == 0) red[wave] = acc;
    __syncthreads();
    if (tid == 0) {
        float s = 0.f;
#pragma unroll
        for (int w = 0; w < 16; ++w) s += red[w];
        out[0] = s / (float)BS;
    }
}

extern "C" void kernel_launch(void* const* d_in, const int* in_sizes, int n_in,
                              void* d_out, int out_size, void* d_ws, size_t ws_size,
                              hipStream_t stream) {
    const float* text = (const float*)d_in[0];
    const float* ctr  = (const float*)d_in[1];

    char* ws = (char*)d_ws;
    const size_t embBytes = (size_t)BS * DIM;   // fp8: 6,291,456 bytes each
    unsigned char* tq = (unsigned char*)ws;
    unsigned char* cq = (unsigned char*)(ws + embBytes);
    float* sim    = (float*)(ws + 2 * embBytes);
    float* rowsum = (float*)(ws + 2 * embBytes + BS * sizeof(float));
    float* colsum = (float*)(ws + 2 * embBytes + 2 * BS * sizeof(float));

    normalize_kernel<<<BS / 4, 256, 0, stream>>>(text, ctr, tq, cq, sim, rowsum, colsum);

    gemm_lse_kernel<<<(BS / BM) * (BS / BM), 512, 0, stream>>>(tq, cq, rowsum, colsum);

    finalize_kernel<<<1, 1024, 0, stream>>>(rowsum, colsum, sim, (float*)d_out);
}